// Round 4
// baseline (197.828 us; speedup 1.0000x reference)
//
#include <hip/hip_runtime.h>

// SNN forward: 2-layer Leaky (subtract reset), BETA=0.95, THRESHOLD=1.0.
// x: [10, B, 4] f32, w1: [5,4] f32, w2: [3,5] f32.
// out: spk2_rec [10,B,3] f32 ++ mem2_rec [10,B,3] f32.
//
// Numerics: replicate numpy float32 semantics exactly (same op sequence as
// the round-2 passing kernel):
//  - dot products: sequential fmaf chain from 0
//  - leaky update: three separately-rounded f32 ops (mul, add, sub),
//    contraction off
//  - spike: (mem > 1.0f)
//
// Perf: 4 batch elements per thread so the 3-float output groups become
// 3 x 16B stores; nontemporal loads/stores (data is touched once).
// Nontemporal builtins need clang vector types, not HIP_vector_type.

#define NUM_STEPS  10
#define NUM_INPUT  4
#define NUM_HIDDEN 5
#define NUM_OUTPUT 3
#define ELEMS      4

typedef float f32x4 __attribute__((ext_vector_type(4)));

__global__ __launch_bounds__(256) void snn_fwd_kernel(
    const float* __restrict__ x,   // [10, B, 4]
    const float* __restrict__ w1,  // [5, 4]
    const float* __restrict__ w2,  // [3, 5]
    float* __restrict__ out,       // spk2 [10,B,3] ++ mem2 [10,B,3]
    int batch)
{
#pragma clang fp contract(off)
    const int g  = blockIdx.x * blockDim.x + threadIdx.x;
    const int b0 = g * ELEMS;
    if (b0 >= batch) return;
    const bool full = (b0 + ELEMS) <= batch;   // batch % 4 == 0 in practice

    // Weights: wave-uniform addresses -> scalar loads, broadcast to lanes.
    float W1[NUM_HIDDEN][NUM_INPUT];
#pragma unroll
    for (int h = 0; h < NUM_HIDDEN; ++h)
#pragma unroll
        for (int i = 0; i < NUM_INPUT; ++i)
            W1[h][i] = w1[h * NUM_INPUT + i];

    float W2[NUM_OUTPUT][NUM_HIDDEN];
#pragma unroll
    for (int o = 0; o < NUM_OUTPUT; ++o)
#pragma unroll
        for (int i = 0; i < NUM_HIDDEN; ++i)
            W2[o][i] = w2[o * NUM_HIDDEN + i];

    float mem1[ELEMS][NUM_HIDDEN] = {};
    float mem2[ELEMS][NUM_OUTPUT] = {};

    const long long B = (long long)batch;
    float* __restrict__ spk_out = out;                                    // [10,B,3]
    float* __restrict__ mem_out = out + (long long)NUM_STEPS * B * NUM_OUTPUT;

    for (int t = 0; t < NUM_STEPS; ++t) {
        // Input rows for the 4 elements: 64B/lane contiguous.
        f32x4 xv[ELEMS];
        const f32x4* xp = reinterpret_cast<const f32x4*>(
            x + ((long long)t * B + b0) * NUM_INPUT);
        if (full) {
#pragma unroll
            for (int e = 0; e < ELEMS; ++e)
                xv[e] = __builtin_nontemporal_load(xp + e);
        } else {
#pragma unroll
            for (int e = 0; e < ELEMS; ++e)
                if (b0 + e < batch) xv[e] = xp[e];
        }

        float so[ELEMS * NUM_OUTPUT];   // spk2 for the 4 elements, packed
        float mo[ELEMS * NUM_OUTPUT];   // mem2 for the 4 elements, packed

#pragma unroll
        for (int e = 0; e < ELEMS; ++e) {
            const float xd[NUM_INPUT] = {xv[e].x, xv[e].y, xv[e].z, xv[e].w};

            // Layer 1: cur1 = x . w1[h], sequential fma from 0.
            float spk1[NUM_HIDDEN];
#pragma unroll
            for (int h = 0; h < NUM_HIDDEN; ++h) {
                float acc = 0.0f;
#pragma unroll
                for (int i = 0; i < NUM_INPUT; ++i)
                    acc = fmaf(xd[i], W1[h][i], acc);
                const float reset = (mem1[e][h] > 1.0f) ? 1.0f : 0.0f;  // prev mem
                const float t1 = __fmul_rn(0.95f, mem1[e][h]);
                const float t2 = __fadd_rn(t1, acc);
                mem1[e][h] = __fsub_rn(t2, reset);
                spk1[h] = (mem1[e][h] > 1.0f) ? 1.0f : 0.0f;
            }

            // Layer 2.
#pragma unroll
            for (int o = 0; o < NUM_OUTPUT; ++o) {
                float acc = 0.0f;
#pragma unroll
                for (int i = 0; i < NUM_HIDDEN; ++i)
                    acc = fmaf(spk1[i], W2[o][i], acc);
                const float reset = (mem2[e][o] > 1.0f) ? 1.0f : 0.0f;
                const float t1 = __fmul_rn(0.95f, mem2[e][o]);
                const float t2 = __fadd_rn(t1, acc);
                mem2[e][o] = __fsub_rn(t2, reset);
                so[e * NUM_OUTPUT + o] = (mem2[e][o] > 1.0f) ? 1.0f : 0.0f;
                mo[e * NUM_OUTPUT + o] = mem2[e][o];
            }
        }

        // 12 contiguous floats per stream -> 3 x 16B nontemporal stores.
        const long long base = ((long long)t * B + b0) * NUM_OUTPUT;
        if (full) {
            f32x4* sp = reinterpret_cast<f32x4*>(spk_out + base);
            f32x4* mp = reinterpret_cast<f32x4*>(mem_out + base);
#pragma unroll
            for (int j = 0; j < 3; ++j) {
                f32x4 sv = {so[4*j], so[4*j+1], so[4*j+2], so[4*j+3]};
                f32x4 mv = {mo[4*j], mo[4*j+1], mo[4*j+2], mo[4*j+3]};
                __builtin_nontemporal_store(sv, sp + j);
                __builtin_nontemporal_store(mv, mp + j);
            }
        } else {
#pragma unroll
            for (int e = 0; e < ELEMS; ++e)
                if (b0 + e < batch)
#pragma unroll
                    for (int o = 0; o < NUM_OUTPUT; ++o) {
                        spk_out[base + e * NUM_OUTPUT + o] = so[e * NUM_OUTPUT + o];
                        mem_out[base + e * NUM_OUTPUT + o] = mo[e * NUM_OUTPUT + o];
                    }
        }
    }
}

extern "C" void kernel_launch(void* const* d_in, const int* in_sizes, int n_in,
                              void* d_out, int out_size, void* d_ws, size_t ws_size,
                              hipStream_t stream)
{
    const float* x  = (const float*)d_in[0];
    const float* w1 = (const float*)d_in[1];
    const float* w2 = (const float*)d_in[2];
    float* out = (float*)d_out;

    const int batch = in_sizes[0] / (NUM_STEPS * NUM_INPUT);

    const int block = 256;
    const int elems_per_block = block * ELEMS;
    const int grid = (batch + elems_per_block - 1) / elems_per_block;
    snn_fwd_kernel<<<grid, block, 0, stream>>>(x, w1, w2, out, batch);
}

// Round 5
// 59.530 us; speedup vs baseline: 3.3232x; 3.3232x over previous
//
#include <hip/hip_runtime.h>

// SNN forward: 2-layer Leaky (subtract reset), BETA=0.95, THRESHOLD=1.0.
// x: [10, B, 4] f32, w1: [5,4] f32, w2: [3,5] f32.
// out: spk2_rec [10,B,3] f32 ++ mem2_rec [10,B,3] f32.
//
// Numerics: bit-identical op sequence to the round-2 passing kernel
// (sequential fmaf dot, unfused mul/add/sub leaky update, mem > 1.0f spike).
//
// Perf: 1 elem/thread compute; per-timestep LDS transpose of the block's
// 256x3 outputs so stores become fully-contiguous f32x4 per lane
// (full 64B lines per wave -> safe for nontemporal streaming stores).
// Round-4 lesson: nt stores with sub-line lane strides cause ~2x HBM
// write amplification (RMW granules). Full-line-per-instruction only.

#define NUM_STEPS  10
#define NUM_INPUT  4
#define NUM_HIDDEN 5
#define NUM_OUTPUT 3
#define BLOCK      256
#define LSTR       257   // LDS row stride (pad) -> gather reads <=2-way conflict

typedef float f32x4 __attribute__((ext_vector_type(4)));

__global__ __launch_bounds__(BLOCK) void snn_fwd_kernel(
    const float* __restrict__ x,   // [10, B, 4]
    const float* __restrict__ w1,  // [5, 4]
    const float* __restrict__ w2,  // [3, 5]
    float* __restrict__ out,       // spk2 [10,B,3] ++ mem2 [10,B,3]
    int batch)
{
#pragma clang fp contract(off)
    const int tid        = threadIdx.x;
    const int block_base = blockIdx.x * BLOCK;
    const int b          = block_base + tid;
    const long long B    = (long long)batch;
    const bool full_block = (block_base + BLOCK) <= batch;

    // Threads past the end only exist in partial blocks, whose path has no
    // barriers -> safe early exit.
    if (b >= batch) return;

    // Weights: wave-uniform addresses -> scalar loads, broadcast to lanes.
    float W1[NUM_HIDDEN][NUM_INPUT];
#pragma unroll
    for (int h = 0; h < NUM_HIDDEN; ++h)
#pragma unroll
        for (int i = 0; i < NUM_INPUT; ++i)
            W1[h][i] = w1[h * NUM_INPUT + i];

    float W2[NUM_OUTPUT][NUM_HIDDEN];
#pragma unroll
    for (int o = 0; o < NUM_OUTPUT; ++o)
#pragma unroll
        for (int i = 0; i < NUM_HIDDEN; ++i)
            W2[o][i] = w2[o * NUM_HIDDEN + i];

    float mem1[NUM_HIDDEN] = {0.f, 0.f, 0.f, 0.f, 0.f};
    float mem2[NUM_OUTPUT] = {0.f, 0.f, 0.f};

    float* __restrict__ spk_out = out;                                    // [10,B,3]
    float* __restrict__ mem_out = out + (long long)NUM_STEPS * B * NUM_OUTPUT;

    // [stream(2)][o(3)][tid] with padded row stride.
    __shared__ float tile[6 * LSTR];

    if (full_block) {
#pragma unroll
        for (int t = 0; t < NUM_STEPS; ++t) {
            // Coalesced 16B/lane load of this timestep's input row.
            const f32x4 xv = reinterpret_cast<const f32x4*>(
                x + ((long long)t * B + block_base) * NUM_INPUT)[tid];
            const float xd[NUM_INPUT] = {xv.x, xv.y, xv.z, xv.w};

            // Layer 1: sequential fma from 0, then unfused leaky update.
            float spk1[NUM_HIDDEN];
#pragma unroll
            for (int h = 0; h < NUM_HIDDEN; ++h) {
                float acc = 0.0f;
#pragma unroll
                for (int i = 0; i < NUM_INPUT; ++i)
                    acc = fmaf(xd[i], W1[h][i], acc);
                const float reset = (mem1[h] > 1.0f) ? 1.0f : 0.0f;  // prev mem
                const float t1 = __fmul_rn(0.95f, mem1[h]);
                const float t2 = __fadd_rn(t1, acc);
                mem1[h] = __fsub_rn(t2, reset);
                spk1[h] = (mem1[h] > 1.0f) ? 1.0f : 0.0f;
            }

            // Layer 2 -> stage outputs in LDS (stride-1 writes, no conflicts).
#pragma unroll
            for (int o = 0; o < NUM_OUTPUT; ++o) {
                float acc = 0.0f;
#pragma unroll
                for (int i = 0; i < NUM_HIDDEN; ++i)
                    acc = fmaf(spk1[i], W2[o][i], acc);
                const float reset = (mem2[o] > 1.0f) ? 1.0f : 0.0f;
                const float t1 = __fmul_rn(0.95f, mem2[o]);
                const float t2 = __fadd_rn(t1, acc);
                mem2[o] = __fsub_rn(t2, reset);
                tile[o * LSTR + tid]       = (mem2[o] > 1.0f) ? 1.0f : 0.0f;
                tile[(o + 3) * LSTR + tid] = mem2[o];
            }

            __syncthreads();

            // Cooperative transposed store: 768 floats per stream = 192 x f32x4.
            // Lane stride 16B, fully contiguous per wave -> nt streaming store.
            if (tid < 192) {
                const long long base = ((long long)t * B + block_base) * NUM_OUTPUT;
                f32x4 sv, mv;
#pragma unroll
                for (int c = 0; c < 4; ++c) {
                    const int f   = tid * 4 + c;     // flat float index in tile
                    const int o   = f % 3;
                    const int src = f / 3;
                    sv[c] = tile[o * LSTR + src];
                    mv[c] = tile[(o + 3) * LSTR + src];
                }
                __builtin_nontemporal_store(
                    sv, reinterpret_cast<f32x4*>(spk_out + base) + tid);
                __builtin_nontemporal_store(
                    mv, reinterpret_cast<f32x4*>(mem_out + base) + tid);
            }

            __syncthreads();   // tile reused next timestep
        }
    } else {
        // Partial tail block: round-2 scalar path (no barriers).
#pragma unroll
        for (int t = 0; t < NUM_STEPS; ++t) {
            const f32x4 xv = *reinterpret_cast<const f32x4*>(
                x + ((long long)t * B + b) * NUM_INPUT);
            const float xd[NUM_INPUT] = {xv.x, xv.y, xv.z, xv.w};

            float spk1[NUM_HIDDEN];
#pragma unroll
            for (int h = 0; h < NUM_HIDDEN; ++h) {
                float acc = 0.0f;
#pragma unroll
                for (int i = 0; i < NUM_INPUT; ++i)
                    acc = fmaf(xd[i], W1[h][i], acc);
                const float reset = (mem1[h] > 1.0f) ? 1.0f : 0.0f;
                const float t1 = __fmul_rn(0.95f, mem1[h]);
                const float t2 = __fadd_rn(t1, acc);
                mem1[h] = __fsub_rn(t2, reset);
                spk1[h] = (mem1[h] > 1.0f) ? 1.0f : 0.0f;
            }

            const long long base = ((long long)t * B + b) * NUM_OUTPUT;
#pragma unroll
            for (int o = 0; o < NUM_OUTPUT; ++o) {
                float acc = 0.0f;
#pragma unroll
                for (int i = 0; i < NUM_HIDDEN; ++i)
                    acc = fmaf(spk1[i], W2[o][i], acc);
                const float reset = (mem2[o] > 1.0f) ? 1.0f : 0.0f;
                const float t1 = __fmul_rn(0.95f, mem2[o]);
                const float t2 = __fadd_rn(t1, acc);
                mem2[o] = __fsub_rn(t2, reset);
                spk_out[base + o] = (mem2[o] > 1.0f) ? 1.0f : 0.0f;
                mem_out[base + o] = mem2[o];
            }
        }
    }
}

extern "C" void kernel_launch(void* const* d_in, const int* in_sizes, int n_in,
                              void* d_out, int out_size, void* d_ws, size_t ws_size,
                              hipStream_t stream)
{
    const float* x  = (const float*)d_in[0];
    const float* w1 = (const float*)d_in[1];
    const float* w2 = (const float*)d_in[2];
    float* out = (float*)d_out;

    const int batch = in_sizes[0] / (NUM_STEPS * NUM_INPUT);

    const int grid = (batch + BLOCK - 1) / BLOCK;
    snn_fwd_kernel<<<grid, BLOCK, 0, stream>>>(x, w1, w2, out, batch);
}